// Round 3
// baseline (1002.312 us; speedup 1.0000x reference)
//
#include <hip/hip_runtime.h>
#include <stdint.h>

// MoE FFN: router(fp64) -> x->bf16 convert -> W transpose/convert ->
// GEMM1(gather-A, gelu) -> GEMM2(split-K, fp32-atomic into d_out).
// m97-style MFMA GEMM: 128x128 tile, BK=32, mfma_f32_16x16x32_bf16,
// global_load_lds width=16, XCD co-location swizzle (m-panel class = bx&7).
// R2: split-K GEMM2 + atomic-out (occupancy 4->8 blk/CU), gather-fused GEMM1.

#define NEXP 7
#define KTOP 2
#define CAP 3072
#define DM 1024
#define HF 4096
#define TT 8192
#define SPLITK 2

typedef __bf16 bf16x8 __attribute__((ext_vector_type(8)));
typedef float f32x4 __attribute__((ext_vector_type(4)));
typedef unsigned short ushort8_t __attribute__((ext_vector_type(8)));

__device__ __forceinline__ unsigned short f2bf(float v) {
  union { float f; unsigned u; } a; a.f = v;
  unsigned r = a.u + 0x7FFFu + ((a.u >> 16) & 1u);   // RNE
  return (unsigned short)(r >> 16);
}
__device__ __forceinline__ float gelu_t(float v) {
  float u = 0.7978845608028654f * (v + 0.044715f * v * v * v);
  float ex = __expf(2.0f * u);
  float th = 1.0f - 2.0f / (ex + 1.0f);
  return 0.5f * v * (1.0f + th);
}
__device__ __forceinline__ void gl2lds16(const void* g, void* l) {
  __builtin_amdgcn_global_load_lds(
      (const __attribute__((address_space(1))) unsigned int*)g,
      (__attribute__((address_space(3))) unsigned int*)l, 16, 0, 0);
}

// one wave per token; fp64 logits so top-2 matches the np reference exactly
__global__ void router_kernel(const float* __restrict__ x, const float* __restrict__ Wg,
                              int* __restrict__ counts, int* __restrict__ tokOfSlot,
                              float* __restrict__ wOfSlot) {
  int wave = threadIdx.x >> 6, lane = threadIdx.x & 63;
  int t = blockIdx.x * 4 + wave;
  double acc[NEXP];
#pragma unroll
  for (int e = 0; e < NEXP; ++e) acc[e] = 0.0;
  const float* xr = x + (long)t * DM;
  for (int j = 0; j < DM / 64; ++j) {
    int d = j * 64 + lane;
    double xv = (double)xr[d];
#pragma unroll
    for (int e = 0; e < NEXP; ++e) acc[e] += xv * (double)Wg[d * NEXP + e];
  }
#pragma unroll
  for (int e = 0; e < NEXP; ++e) {
#pragma unroll
    for (int off = 32; off > 0; off >>= 1) acc[e] += __shfl_down(acc[e], off);
  }
  if (lane == 0) {
    int i1 = 0; double l1 = acc[0];
    for (int e2 = 1; e2 < NEXP; ++e2) if (acc[e2] > l1) { l1 = acc[e2]; i1 = e2; }
    int i2 = -1; double l2 = -1e300;
    for (int e2 = 0; e2 < NEXP; ++e2) if (e2 != i1 && acc[e2] > l2) { l2 = acc[e2]; i2 = e2; }
    float w1 = (float)(1.0 / (1.0 + exp(l2 - l1)));
    float w2 = 1.0f - w1;
    int p0 = atomicAdd(&counts[i1], 1);
    if (p0 < CAP) { tokOfSlot[i1 * CAP + p0] = t * 2;     wOfSlot[i1 * CAP + p0] = w1; }
    int p1 = atomicAdd(&counts[i2], 1);
    if (p1 < CAP) { tokOfSlot[i2 * CAP + p1] = t * 2 + 1; wOfSlot[i2 * CAP + p1] = w2; }
  }
}

// streaming fp32 -> bf16 convert, 8 elems/thread
__global__ void cvt_x(const float* __restrict__ in, unsigned short* __restrict__ out) {
  long i = (long)blockIdx.x * 2048 + (long)threadIdx.x * 8;
  float4 a = ((const float4*)(in + i))[0];
  float4 b = ((const float4*)(in + i))[1];
  ushort8_t v;
  v[0] = f2bf(a.x); v[1] = f2bf(a.y); v[2] = f2bf(a.z); v[3] = f2bf(a.w);
  v[4] = f2bf(b.x); v[5] = f2bf(b.y); v[6] = f2bf(b.z); v[7] = f2bf(b.w);
  *(ushort8_t*)(out + i) = v;
}

// [R][C] fp32 -> [C][R] bf16, 64x64 LDS tile (pad 65), 16B vector writes
__global__ void transcvt(const float* __restrict__ in, unsigned short* __restrict__ out,
                         int R, int C) {
  __shared__ float tile[64][65];
  long base = (long)blockIdx.z * (long)R * (long)C;
  const float* inp = in + base;
  unsigned short* outp = out + base;
  int c0 = blockIdx.x * 64, r0 = blockIdx.y * 64;
  int lx = threadIdx.x & 63, ly = threadIdx.x >> 6;
#pragma unroll
  for (int i = 0; i < 16; ++i) {
    int r = ly + i * 4;
    tile[r][lx] = inp[(long)(r0 + r) * C + c0 + lx];
  }
  __syncthreads();
  int cl = threadIdx.x >> 3;        // 0..31
  int rb = (threadIdx.x & 7) * 8;   // 0..56
#pragma unroll
  for (int h = 0; h < 2; ++h) {
    int c = cl + 32 * h;
    ushort8_t v;
#pragma unroll
    for (int j = 0; j < 8; ++j) v[j] = f2bf(tile[rb + j][c]);
    *(ushort8_t*)&outp[(long)(c0 + c) * R + r0 + rb] = v;  // 16B aligned
  }
}

// GEMM1: h[e][m][n] = gelu( xc[tok(e,m)] @ Wb1[e][n] ), A gathered via tokOfSlot
__global__ __launch_bounds__(256, 2) void gemm1_ffn(
    const unsigned short* __restrict__ xc, const unsigned short* __restrict__ Wb1,
    unsigned short* __restrict__ hb, const int* __restrict__ counts,
    const int* __restrict__ tokOfSlot) {
  constexpr int TN = HF / 128;   // 32
  __shared__ unsigned short sA[128 * 32];
  __shared__ unsigned short sB[128 * 32];
  int e = blockIdx.z;
  int mcnt = counts[e]; mcnt = mcnt < CAP ? mcnt : CAP;
  int bx = blockIdx.x;
  int cls = bx & 7, step = bx >> 3;
  int m0 = (cls + 8 * (step / TN)) * 128;
  if (m0 >= mcnt) return;
  int n0 = (step % TN) * 128;
  const unsigned short* Be = Wb1 + (long)e * HF * DM;

  int tid = threadIdx.x;
  int lane = tid & 63, wave = tid >> 6;
  int lm = lane & 15, quad = lane >> 4;
  int wm = (wave & 1) * 64, wn = (wave >> 1) * 64;

  int ra = tid >> 2, ca = (tid & 3) * 8;
  int r0 = m0 + ra, r1 = m0 + 64 + ra;
  int tok0 = (r0 < mcnt) ? (tokOfSlot[e * CAP + r0] >> 1) : 0;
  int tok1 = (r1 < mcnt) ? (tokOfSlot[e * CAP + r1] >> 1) : 0;
  const unsigned short* Ab0 = xc + (long)tok0 * DM + ca;
  const unsigned short* Ab1 = xc + (long)tok1 * DM + ca;
  const unsigned short* Bb0 = Be + (long)(n0 + ra) * DM + ca;
  const unsigned short* Bb1 = Be + (long)(n0 + 64 + ra) * DM + ca;
  unsigned short* sAp0 = &sA[tid * 8];
  unsigned short* sAp1 = &sA[(tid + 256) * 8];
  unsigned short* sBp0 = &sB[tid * 8];
  unsigned short* sBp1 = &sB[(tid + 256) * 8];

  f32x4 acc[4][4];
#pragma unroll
  for (int i = 0; i < 4; ++i)
#pragma unroll
    for (int j = 0; j < 4; ++j) acc[i][j] = f32x4{0.f, 0.f, 0.f, 0.f};

  for (int k0 = 0; k0 < DM; k0 += 32) {
    gl2lds16(Ab0 + k0, sAp0);
    gl2lds16(Ab1 + k0, sAp1);
    gl2lds16(Bb0 + k0, sBp0);
    gl2lds16(Bb1 + k0, sBp1);
    __syncthreads();
    bf16x8 aF[4], bF[4];
#pragma unroll
    for (int mi = 0; mi < 4; ++mi)
      aF[mi] = *(const bf16x8*)&sA[(wm + mi * 16 + lm) * 32 + quad * 8];
#pragma unroll
    for (int ni = 0; ni < 4; ++ni)
      bF[ni] = *(const bf16x8*)&sB[(wn + ni * 16 + lm) * 32 + quad * 8];
#pragma unroll
    for (int mi = 0; mi < 4; ++mi)
#pragma unroll
      for (int ni = 0; ni < 4; ++ni)
        acc[mi][ni] = __builtin_amdgcn_mfma_f32_16x16x32_bf16(aF[mi], bF[ni], acc[mi][ni], 0, 0, 0);
    __syncthreads();
  }

  unsigned short* Ce = hb + (long)e * CAP * HF;
#pragma unroll
  for (int mi = 0; mi < 4; ++mi) {
    int mb = m0 + wm + mi * 16 + quad * 4;
#pragma unroll
    for (int r = 0; r < 4; ++r) {
      int m = mb + r;
      if (m < mcnt) {
#pragma unroll
        for (int ni = 0; ni < 4; ++ni) {
          int n = n0 + wn + ni * 16 + lm;
          Ce[(long)m * HF + n] = f2bf(gelu_t(acc[mi][ni][r]));
        }
      }
    }
  }
}

// GEMM2: out[tok] += w * (hb[e][m] @ Wb2[e][n]), split-K, fp32 HW atomics
__global__ __launch_bounds__(256, 2) void gemm2_out(
    const unsigned short* __restrict__ hb, const unsigned short* __restrict__ Wb2,
    float* __restrict__ out, const int* __restrict__ counts,
    const int* __restrict__ tokOfSlot, const float* __restrict__ wOfSlot) {
  constexpr int TN = DM / 128;   // 8
  __shared__ unsigned short sA[128 * 32];
  __shared__ unsigned short sB[128 * 32];
  int e = blockIdx.z;
  int mcnt = counts[e]; mcnt = mcnt < CAP ? mcnt : CAP;
  int bx = blockIdx.x;
  int cls = bx & 7, step = bx >> 3;
  int m0 = (cls + 8 * (step / TN)) * 128;
  if (m0 >= mcnt) return;
  int n0 = (step % TN) * 128;
  int kbase = blockIdx.y * (HF / SPLITK);
  const unsigned short* Ae = hb + (long)e * CAP * HF + kbase;
  const unsigned short* Be = Wb2 + (long)e * DM * HF + kbase;

  int tid = threadIdx.x;
  int lane = tid & 63, wave = tid >> 6;
  int lm = lane & 15, quad = lane >> 4;
  int wm = (wave & 1) * 64, wn = (wave >> 1) * 64;

  int ra = tid >> 2, ca = (tid & 3) * 8;
  const unsigned short* Ab0 = Ae + (long)(m0 + ra) * HF + ca;
  const unsigned short* Ab1 = Ae + (long)(m0 + 64 + ra) * HF + ca;
  const unsigned short* Bb0 = Be + (long)(n0 + ra) * HF + ca;
  const unsigned short* Bb1 = Be + (long)(n0 + 64 + ra) * HF + ca;
  unsigned short* sAp0 = &sA[tid * 8];
  unsigned short* sAp1 = &sA[(tid + 256) * 8];
  unsigned short* sBp0 = &sB[tid * 8];
  unsigned short* sBp1 = &sB[(tid + 256) * 8];

  f32x4 acc[4][4];
#pragma unroll
  for (int i = 0; i < 4; ++i)
#pragma unroll
    for (int j = 0; j < 4; ++j) acc[i][j] = f32x4{0.f, 0.f, 0.f, 0.f};

  for (int k0 = 0; k0 < HF / SPLITK; k0 += 32) {
    gl2lds16(Ab0 + k0, sAp0);
    gl2lds16(Ab1 + k0, sAp1);
    gl2lds16(Bb0 + k0, sBp0);
    gl2lds16(Bb1 + k0, sBp1);
    __syncthreads();
    bf16x8 aF[4], bF[4];
#pragma unroll
    for (int mi = 0; mi < 4; ++mi)
      aF[mi] = *(const bf16x8*)&sA[(wm + mi * 16 + lm) * 32 + quad * 8];
#pragma unroll
    for (int ni = 0; ni < 4; ++ni)
      bF[ni] = *(const bf16x8*)&sB[(wn + ni * 16 + lm) * 32 + quad * 8];
#pragma unroll
    for (int mi = 0; mi < 4; ++mi)
#pragma unroll
      for (int ni = 0; ni < 4; ++ni)
        acc[mi][ni] = __builtin_amdgcn_mfma_f32_16x16x32_bf16(aF[mi], bF[ni], acc[mi][ni], 0, 0, 0);
    __syncthreads();
  }

#pragma unroll
  for (int mi = 0; mi < 4; ++mi) {
    int mb = m0 + wm + mi * 16 + quad * 4;
#pragma unroll
    for (int r = 0; r < 4; ++r) {
      int m = mb + r;
      if (m < mcnt) {
        int t = tokOfSlot[e * CAP + m] >> 1;
        float w = wOfSlot[e * CAP + m];
        float* orow = out + (long)t * DM;
#pragma unroll
        for (int ni = 0; ni < 4; ++ni) {
          int n = n0 + wn + ni * 16 + lm;
          unsafeAtomicAdd(&orow[n], w * acc[mi][ni][r]);
        }
      }
    }
  }
}

extern "C" void kernel_launch(void* const* d_in, const int* in_sizes, int n_in,
                              void* d_out, int out_size, void* d_ws, size_t ws_size,
                              hipStream_t stream) {
  const float* x  = (const float*)d_in[0];
  const float* Wg = (const float*)d_in[1];
  const float* W1 = (const float*)d_in[2];
  const float* W2 = (const float*)d_in[3];
  float* out = (float*)d_out;

  char* ws = (char*)d_ws;
  size_t off = 0;
  auto alloc = [&](size_t b) { void* p = ws + off; off = (off + b + 255) & ~(size_t)255; return p; };
  int* counts            = (int*)alloc(NEXP * 4);
  int* tokOfSlot         = (int*)alloc((size_t)NEXP * CAP * 4);
  float* wOfSlot         = (float*)alloc((size_t)NEXP * CAP * 4);
  unsigned short* Wb1    = (unsigned short*)alloc((size_t)NEXP * DM * HF * 2);  // [E][H][D]
  unsigned short* Wb2    = (unsigned short*)alloc((size_t)NEXP * DM * HF * 2);  // [E][D][H]
  unsigned short* xc     = (unsigned short*)alloc((size_t)TT * DM * 2);         // [T][D] bf16
  unsigned short* hb     = (unsigned short*)alloc((size_t)NEXP * CAP * HF * 2); // [E][CAP][H]

  hipMemsetAsync(counts, 0, NEXP * sizeof(int), stream);
  hipMemsetAsync(out, 0, (size_t)TT * DM * sizeof(float), stream);
  router_kernel<<<TT / 4, 256, 0, stream>>>(x, Wg, counts, tokOfSlot, wOfSlot);
  cvt_x<<<(TT * DM) / 2048, 256, 0, stream>>>(x, xc);
  transcvt<<<dim3(HF / 64, DM / 64, NEXP), 256, 0, stream>>>(W1, Wb1, DM, HF);
  transcvt<<<dim3(DM / 64, HF / 64, NEXP), 256, 0, stream>>>(W2, Wb2, HF, DM);

  constexpr int TM = CAP / 128;  // 24
  gemm1_ffn<<<dim3(TM * (HF / 128), 1, NEXP), 256, 0, stream>>>(xc, Wb1, hb, counts, tokOfSlot);
  gemm2_out<<<dim3(TM * (DM / 128), SPLITK, NEXP), 256, 0, stream>>>(hb, Wb2, out, counts,
                                                                    tokOfSlot, wOfSlot);
}

// Round 4
// 992.967 us; speedup vs baseline: 1.0094x; 1.0094x over previous
//
#include <hip/hip_runtime.h>
#include <stdint.h>

// MoE FFN: router(fp64, fused x->bf16) -> W transpose/convert ->
// GEMM1(gather-A, gelu) -> GEMM2(split-K, fp32-atomic into d_out).
// R3->R4: software-pipelined K-loop: double-buffered LDS, prefetch distance 1,
// raw asm barriers (s_waitcnt vmcnt(4); s_barrier) to bypass the compiler's
// vmcnt(0) drain before s_barrier (the ~80% idle in R3's 19% MfmaUtil).

#define NEXP 7
#define KTOP 2
#define CAP 3072
#define DM 1024
#define HF 4096
#define TT 8192
#define SPLITK 2
#define BK 32

typedef __bf16 bf16x8 __attribute__((ext_vector_type(8)));
typedef float f32x4 __attribute__((ext_vector_type(4)));
typedef unsigned short ushort8_t __attribute__((ext_vector_type(8)));

__device__ __forceinline__ unsigned short f2bf(float v) {
  union { float f; unsigned u; } a; a.f = v;
  unsigned r = a.u + 0x7FFFu + ((a.u >> 16) & 1u);   // RNE
  return (unsigned short)(r >> 16);
}
__device__ __forceinline__ float gelu_t(float v) {
  float u = 0.7978845608028654f * (v + 0.044715f * v * v * v);
  float ex = __expf(2.0f * u);
  float th = 1.0f - 2.0f / (ex + 1.0f);
  return 0.5f * v * (1.0f + th);
}
__device__ __forceinline__ void gl2lds16(const void* g, void* l) {
  __builtin_amdgcn_global_load_lds(
      (const __attribute__((address_space(1))) unsigned int*)g,
      (__attribute__((address_space(3))) unsigned int*)l, 16, 0, 0);
}

// one wave per token; fp64 logits (top-2 matches np ref); also emits xc bf16
__global__ void router_kernel(const float* __restrict__ x, const float* __restrict__ Wg,
                              int* __restrict__ counts, int* __restrict__ tokOfSlot,
                              float* __restrict__ wOfSlot, unsigned short* __restrict__ xc) {
  int wave = threadIdx.x >> 6, lane = threadIdx.x & 63;
  int t = blockIdx.x * 4 + wave;
  double acc[NEXP];
#pragma unroll
  for (int e = 0; e < NEXP; ++e) acc[e] = 0.0;
  const float* xr = x + (long)t * DM;
#pragma unroll
  for (int it = 0; it < 2; ++it) {
    int d0 = it * 512 + lane * 8;
    float4 a = ((const float4*)(xr + d0))[0];
    float4 b = ((const float4*)(xr + d0))[1];
    float v[8] = {a.x, a.y, a.z, a.w, b.x, b.y, b.z, b.w};
    ushort8_t o;
#pragma unroll
    for (int j = 0; j < 8; ++j) {
      o[j] = f2bf(v[j]);
      double xv = (double)v[j];
#pragma unroll
      for (int e = 0; e < NEXP; ++e) acc[e] += xv * (double)Wg[(d0 + j) * NEXP + e];
    }
    *(ushort8_t*)(xc + (long)t * DM + d0) = o;
  }
#pragma unroll
  for (int e = 0; e < NEXP; ++e) {
#pragma unroll
    for (int off = 32; off > 0; off >>= 1) acc[e] += __shfl_down(acc[e], off);
  }
  if (lane == 0) {
    int i1 = 0; double l1 = acc[0];
    for (int e2 = 1; e2 < NEXP; ++e2) if (acc[e2] > l1) { l1 = acc[e2]; i1 = e2; }
    int i2 = -1; double l2 = -1e300;
    for (int e2 = 0; e2 < NEXP; ++e2) if (e2 != i1 && acc[e2] > l2) { l2 = acc[e2]; i2 = e2; }
    float w1 = (float)(1.0 / (1.0 + exp(l2 - l1)));
    float w2 = 1.0f - w1;
    int p0 = atomicAdd(&counts[i1], 1);
    if (p0 < CAP) { tokOfSlot[i1 * CAP + p0] = t; wOfSlot[i1 * CAP + p0] = w1; }
    int p1 = atomicAdd(&counts[i2], 1);
    if (p1 < CAP) { tokOfSlot[i2 * CAP + p1] = t; wOfSlot[i2 * CAP + p1] = w2; }
  }
}

// [R][C] fp32 -> [C][R] bf16, 64x64 LDS tile (pad 65), 16B vector writes
__global__ void transcvt(const float* __restrict__ in, unsigned short* __restrict__ out,
                         int R, int C) {
  __shared__ float tile[64][65];
  long base = (long)blockIdx.z * (long)R * (long)C;
  const float* inp = in + base;
  unsigned short* outp = out + base;
  int c0 = blockIdx.x * 64, r0 = blockIdx.y * 64;
  int lx = threadIdx.x & 63, ly = threadIdx.x >> 6;
#pragma unroll
  for (int i = 0; i < 16; ++i) {
    int r = ly + i * 4;
    tile[r][lx] = inp[(long)(r0 + r) * C + c0 + lx];
  }
  __syncthreads();
  int cl = threadIdx.x >> 3;
  int rb = (threadIdx.x & 7) * 8;
#pragma unroll
  for (int h = 0; h < 2; ++h) {
    int c = cl + 32 * h;
    ushort8_t v;
#pragma unroll
    for (int j = 0; j < 8; ++j) v[j] = f2bf(tile[rb + j][c]);
    *(ushort8_t*)&outp[(long)(c0 + c) * R + r0 + rb] = v;
  }
}

#define PIPE_BARRIER_TOP()  asm volatile("s_barrier" ::: "memory")
#define PIPE_WAIT4_BAR()    asm volatile("s_waitcnt vmcnt(4)\n\ts_barrier" ::: "memory")
#define PIPE_WAIT0_BAR()    asm volatile("s_waitcnt vmcnt(0)\n\ts_barrier" ::: "memory")

// GEMM1: h[e][m][n] = gelu( xc[tok(e,m)] @ Wb1[e][n] ), A gathered via tokOfSlot
__global__ __launch_bounds__(256, 2) void gemm1_ffn(
    const unsigned short* __restrict__ xc, const unsigned short* __restrict__ Wb1,
    unsigned short* __restrict__ hb, const int* __restrict__ counts,
    const int* __restrict__ tokOfSlot) {
  constexpr int TN = HF / 128;   // 32
  __shared__ unsigned short sA[2][128 * BK];
  __shared__ unsigned short sB[2][128 * BK];
  int e = blockIdx.z;
  int mcnt = counts[e]; mcnt = mcnt < CAP ? mcnt : CAP;
  int bx = blockIdx.x;
  int cls = bx & 7, step = bx >> 3;
  int m0 = (cls + 8 * (step / TN)) * 128;
  if (m0 >= mcnt) return;
  int n0 = (step % TN) * 128;
  const unsigned short* Be = Wb1 + (long)e * HF * DM;

  int tid = threadIdx.x;
  int lane = tid & 63, wave = tid >> 6;
  int lm = lane & 15, quad = lane >> 4;
  int wm = (wave & 1) * 64, wn = (wave >> 1) * 64;

  int ra = tid >> 2, ca = (tid & 3) * 8;
  int r0 = m0 + ra, r1 = m0 + 64 + ra;
  int tok0 = (r0 < mcnt) ? tokOfSlot[e * CAP + r0] : 0;
  int tok1 = (r1 < mcnt) ? tokOfSlot[e * CAP + r1] : 0;
  const unsigned short* Ab0 = xc + (long)tok0 * DM + ca;
  const unsigned short* Ab1 = xc + (long)tok1 * DM + ca;
  const unsigned short* Bb0 = Be + (long)(n0 + ra) * DM + ca;
  const unsigned short* Bb1 = Be + (long)(n0 + 64 + ra) * DM + ca;

  f32x4 acc[4][4];
#pragma unroll
  for (int i = 0; i < 4; ++i)
#pragma unroll
    for (int j = 0; j < 4; ++j) acc[i][j] = f32x4{0.f, 0.f, 0.f, 0.f};

  // prologue: stage k=0 into set 0
  gl2lds16(Ab0, &sA[0][tid * 8]);
  gl2lds16(Ab1, &sA[0][(tid + 256) * 8]);
  gl2lds16(Bb0, &sB[0][tid * 8]);
  gl2lds16(Bb1, &sB[0][(tid + 256) * 8]);

  for (int k0 = 0; k0 < DM; k0 += BK) {
    int cur = (k0 >> 5) & 1, nxt = cur ^ 1;
    PIPE_BARRIER_TOP();               // WAR: prior iter's ds_reads done (all waves)
    if (k0 + BK < DM) {
      int kn = k0 + BK;
      gl2lds16(Ab0 + kn, &sA[nxt][tid * 8]);
      gl2lds16(Ab1 + kn, &sA[nxt][(tid + 256) * 8]);
      gl2lds16(Bb0 + kn, &sB[nxt][tid * 8]);
      gl2lds16(Bb1 + kn, &sB[nxt][(tid + 256) * 8]);
      PIPE_WAIT4_BAR();               // wait only cur's 4 loads; nxt stays in flight
    } else {
      PIPE_WAIT0_BAR();
    }
    bf16x8 aF[4], bF[4];
#pragma unroll
    for (int mi = 0; mi < 4; ++mi)
      aF[mi] = *(const bf16x8*)&sA[cur][(wm + mi * 16 + lm) * BK + quad * 8];
#pragma unroll
    for (int ni = 0; ni < 4; ++ni)
      bF[ni] = *(const bf16x8*)&sB[cur][(wn + ni * 16 + lm) * BK + quad * 8];
#pragma unroll
    for (int mi = 0; mi < 4; ++mi)
#pragma unroll
      for (int ni = 0; ni < 4; ++ni)
        acc[mi][ni] = __builtin_amdgcn_mfma_f32_16x16x32_bf16(aF[mi], bF[ni], acc[mi][ni], 0, 0, 0);
  }

  unsigned short* Ce = hb + (long)e * CAP * HF;
#pragma unroll
  for (int mi = 0; mi < 4; ++mi) {
    int mb = m0 + wm + mi * 16 + quad * 4;
#pragma unroll
    for (int r = 0; r < 4; ++r) {
      int m = mb + r;
      if (m < mcnt) {
#pragma unroll
        for (int ni = 0; ni < 4; ++ni) {
          int n = n0 + wn + ni * 16 + lm;
          Ce[(long)m * HF + n] = f2bf(gelu_t(acc[mi][ni][r]));
        }
      }
    }
  }
}

// GEMM2: out[tok] += w * (hb[e][m] @ Wb2[e][n]), split-K, fp32 HW atomics
__global__ __launch_bounds__(256, 2) void gemm2_out(
    const unsigned short* __restrict__ hb, const unsigned short* __restrict__ Wb2,
    float* __restrict__ out, const int* __restrict__ counts,
    const int* __restrict__ tokOfSlot, const float* __restrict__ wOfSlot) {
  constexpr int TN = DM / 128;   // 8
  constexpr int KS = HF / SPLITK;
  __shared__ unsigned short sA[2][128 * BK];
  __shared__ unsigned short sB[2][128 * BK];
  int e = blockIdx.z;
  int mcnt = counts[e]; mcnt = mcnt < CAP ? mcnt : CAP;
  int bx = blockIdx.x;
  int cls = bx & 7, step = bx >> 3;
  int m0 = (cls + 8 * (step / TN)) * 128;
  if (m0 >= mcnt) return;
  int n0 = (step % TN) * 128;
  int kbase = blockIdx.y * KS;
  const unsigned short* Ae = hb + (long)e * CAP * HF + kbase;
  const unsigned short* Be = Wb2 + (long)e * DM * HF + kbase;

  int tid = threadIdx.x;
  int lane = tid & 63, wave = tid >> 6;
  int lm = lane & 15, quad = lane >> 4;
  int wm = (wave & 1) * 64, wn = (wave >> 1) * 64;

  int ra = tid >> 2, ca = (tid & 3) * 8;
  const unsigned short* Ab0 = Ae + (long)(m0 + ra) * HF + ca;
  const unsigned short* Ab1 = Ae + (long)(m0 + 64 + ra) * HF + ca;
  const unsigned short* Bb0 = Be + (long)(n0 + ra) * HF + ca;
  const unsigned short* Bb1 = Be + (long)(n0 + 64 + ra) * HF + ca;

  f32x4 acc[4][4];
#pragma unroll
  for (int i = 0; i < 4; ++i)
#pragma unroll
    for (int j = 0; j < 4; ++j) acc[i][j] = f32x4{0.f, 0.f, 0.f, 0.f};

  gl2lds16(Ab0, &sA[0][tid * 8]);
  gl2lds16(Ab1, &sA[0][(tid + 256) * 8]);
  gl2lds16(Bb0, &sB[0][tid * 8]);
  gl2lds16(Bb1, &sB[0][(tid + 256) * 8]);

  for (int k0 = 0; k0 < KS; k0 += BK) {
    int cur = (k0 >> 5) & 1, nxt = cur ^ 1;
    PIPE_BARRIER_TOP();
    if (k0 + BK < KS) {
      int kn = k0 + BK;
      gl2lds16(Ab0 + kn, &sA[nxt][tid * 8]);
      gl2lds16(Ab1 + kn, &sA[nxt][(tid + 256) * 8]);
      gl2lds16(Bb0 + kn, &sB[nxt][tid * 8]);
      gl2lds16(Bb1 + kn, &sB[nxt][(tid + 256) * 8]);
      PIPE_WAIT4_BAR();
    } else {
      PIPE_WAIT0_BAR();
    }
    bf16x8 aF[4], bF[4];
#pragma unroll
    for (int mi = 0; mi < 4; ++mi)
      aF[mi] = *(const bf16x8*)&sA[cur][(wm + mi * 16 + lm) * BK + quad * 8];
#pragma unroll
    for (int ni = 0; ni < 4; ++ni)
      bF[ni] = *(const bf16x8*)&sB[cur][(wn + ni * 16 + lm) * BK + quad * 8];
#pragma unroll
    for (int mi = 0; mi < 4; ++mi)
#pragma unroll
      for (int ni = 0; ni < 4; ++ni)
        acc[mi][ni] = __builtin_amdgcn_mfma_f32_16x16x32_bf16(aF[mi], bF[ni], acc[mi][ni], 0, 0, 0);
  }

#pragma unroll
  for (int mi = 0; mi < 4; ++mi) {
    int mb = m0 + wm + mi * 16 + quad * 4;
#pragma unroll
    for (int r = 0; r < 4; ++r) {
      int m = mb + r;
      if (m < mcnt) {
        int t = tokOfSlot[e * CAP + m];
        float w = wOfSlot[e * CAP + m];
        float* orow = out + (long)t * DM;
#pragma unroll
        for (int ni = 0; ni < 4; ++ni) {
          int n = n0 + wn + ni * 16 + lm;
          unsafeAtomicAdd(&orow[n], w * acc[mi][ni][r]);
        }
      }
    }
  }
}

extern "C" void kernel_launch(void* const* d_in, const int* in_sizes, int n_in,
                              void* d_out, int out_size, void* d_ws, size_t ws_size,
                              hipStream_t stream) {
  const float* x  = (const float*)d_in[0];
  const float* Wg = (const float*)d_in[1];
  const float* W1 = (const float*)d_in[2];
  const float* W2 = (const float*)d_in[3];
  float* out = (float*)d_out;

  char* ws = (char*)d_ws;
  size_t off = 0;
  auto alloc = [&](size_t b) { void* p = ws + off; off = (off + b + 255) & ~(size_t)255; return p; };
  int* counts            = (int*)alloc(NEXP * 4);
  int* tokOfSlot         = (int*)alloc((size_t)NEXP * CAP * 4);
  float* wOfSlot         = (float*)alloc((size_t)NEXP * CAP * 4);
  unsigned short* Wb1    = (unsigned short*)alloc((size_t)NEXP * DM * HF * 2);  // [E][H][D]
  unsigned short* Wb2    = (unsigned short*)alloc((size_t)NEXP * DM * HF * 2);  // [E][D][H]
  unsigned short* xc     = (unsigned short*)alloc((size_t)TT * DM * 2);         // [T][D] bf16
  unsigned short* hb     = (unsigned short*)alloc((size_t)NEXP * CAP * HF * 2); // [E][CAP][H]

  hipMemsetAsync(counts, 0, NEXP * sizeof(int), stream);
  hipMemsetAsync(out, 0, (size_t)TT * DM * sizeof(float), stream);
  router_kernel<<<TT / 4, 256, 0, stream>>>(x, Wg, counts, tokOfSlot, wOfSlot, xc);
  transcvt<<<dim3(HF / 64, DM / 64, NEXP), 256, 0, stream>>>(W1, Wb1, DM, HF);
  transcvt<<<dim3(DM / 64, HF / 64, NEXP), 256, 0, stream>>>(W2, Wb2, HF, DM);

  constexpr int TM = CAP / 128;  // 24
  gemm1_ffn<<<dim3(TM * (HF / 128), 1, NEXP), 256, 0, stream>>>(xc, Wb1, hb, counts, tokOfSlot);
  gemm2_out<<<dim3(TM * (DM / 128), SPLITK, NEXP), 256, 0, stream>>>(hb, Wb2, out, counts,
                                                                    tokOfSlot, wOfSlot);
}